// Round 10
// baseline (870.833 us; speedup 1.0000x reference)
//
#include <hip/hip_runtime.h>
#include <hip/hip_fp16.h>
#include <math.h>

#define NN 131072
#define NE 2097152
#define NG 16384

__device__ __forceinline__ float lrelu(float x, float s) { return fmaxf(x, s * x); }

template <int H>
__device__ __forceinline__ float sel_h(const float* a, int hsel) {
    if constexpr (H == 1) return a[0];
    else return hsel == 0 ? a[0] : hsel == 1 ? a[1] : hsel == 2 ? a[2] : a[3];
}

// ---------------- CSR build ----------------
__global__ void k_hist(const int* __restrict__ dst, int* __restrict__ cnt, int* __restrict__ rank) {
    int e = blockIdx.x * 256 + threadIdx.x;
    rank[e] = atomicAdd(&cnt[dst[e]], 1);
}

__global__ void k_scan1(const int* __restrict__ cnt, int* __restrict__ rowptr, int* __restrict__ part) {
    __shared__ int s[256];
    int t = threadIdx.x;
    int i = blockIdx.x * 256 + t;
    int v = cnt[i];
    s[t] = v;
    __syncthreads();
    for (int off = 1; off < 256; off <<= 1) {
        int x = (t >= off) ? s[t - off] : 0;
        __syncthreads();
        s[t] += x;
        __syncthreads();
    }
    rowptr[i] = s[t] - v;  // exclusive
    if (t == 255) part[blockIdx.x] = s[255];
}

// scan of block partials + per-layer attention-edge constants ce[h] = dot(We[h], ae[h])
__global__ void k_scan2(int* part,
                        const float* __restrict__ We1, const float* __restrict__ ae1,
                        const float* __restrict__ We2, const float* __restrict__ ae2,
                        const float* __restrict__ We3, const float* __restrict__ ae3,
                        const float* __restrict__ We4, const float* __restrict__ ae4,
                        float* __restrict__ ceb) {
    __shared__ int s[512];
    int t = threadIdx.x;
    int v = part[t];
    s[t] = v;
    __syncthreads();
    for (int off = 1; off < 512; off <<= 1) {
        int x = (t >= off) ? s[t - off] : 0;
        __syncthreads();
        s[t] += x;
        __syncthreads();
    }
    part[t] = s[t] - v;  // exclusive
    if (t < 4) {
        float c = 0.f;
        for (int i = 0; i < 16; i++) c += We1[t * 16 + i] * ae1[t * 16 + i];
        ceb[t] = c;
    } else if (t < 8) {
        int h = t - 4;
        float c = 0.f;
        for (int i = 0; i < 32; i++) c += We2[h * 32 + i] * ae2[h * 32 + i];
        ceb[t] = c;
    } else if (t < 12) {
        int h = t - 8;
        float c = 0.f;
        for (int i = 0; i < 16; i++) c += We3[h * 16 + i] * ae3[h * 16 + i];
        ceb[t] = c;
    } else if (t == 12) {
        float c = 0.f;
        for (int i = 0; i < 50; i++) c += We4[i] * ae4[i];
        ceb[t] = c;
    }
}

__global__ void k_scan3(int* __restrict__ rowptr, const int* __restrict__ part) {
    int t = threadIdx.x;
    int i = blockIdx.x * 256 + t;
    rowptr[i] = rowptr[i] + part[blockIdx.x];
    if (i == 0) rowptr[NN] = NE;
}

// scatter edges into dst-sorted order (no atomics), packing (src, ew) into one uint
__global__ void k_scatter(const int* __restrict__ src, const int* __restrict__ dst,
                          const float* __restrict__ ew, const int* __restrict__ rowptr,
                          const int* __restrict__ rank, unsigned int* __restrict__ ep) {
    int e = blockIdx.x * 256 + threadIdx.x;
    int d = dst[e];
    int p = rowptr[d] + rank[e];
    unsigned int s = (unsigned int)src[e];
    unsigned int q = (unsigned int)(ew[e] * 32767.f + 0.5f);
    __builtin_nontemporal_store((s << 15) | (q & 0x7fffu), &ep[p]);
}

__device__ __forceinline__ void ep_unpack(unsigned int u, int& s, float& w) {
    s = (int)(u >> 15);
    w = (float)(u & 0x7fffu) * (1.f / 32767.f);
}

// ---------------- node transform + fused alpha projections (register-tiled GEMM) ----------------
// TIN = float (layer 1 input) or __half (fp16 inter-layer activations).
template <typename TIN, int FIN, int F, int FR, int H, int C, int ITER>
__global__ __launch_bounds__(256) void k_transform(
    const TIN* __restrict__ in, const float* __restrict__ W,
    const float* __restrict__ as_, const float* __restrict__ ad_,
    __half* __restrict__ h, float* __restrict__ alpha_s, float* __restrict__ alpha_d) {
    constexpr int TF = F / 16;   // features per thread
    constexpr int XS = 65;       // Xl row stride (floats)
    __shared__ float Wl[FIN * F];
    __shared__ float Xl[FIN * XS];
    int t = threadIdx.x;
    int tfg = t & 15;   // feature group
    int ng = t >> 4;    // node group (0..15)
    int f0 = tfg * TF;

    for (int i = t; i < FIN * F; i += 256) {
        int ff = i % F;
        Wl[i] = (ff < FR) ? W[(i / F) * FR + ff] : 0.f;
    }
    float asf[TF], adf[TF];
#pragma unroll
    for (int j = 0; j < TF; j++) {
        bool v = (f0 + j) < FR;
        asf[j] = v ? as_[f0 + j] : 0.f;
        adf[j] = v ? ad_[f0 + j] : 0.f;
    }

    for (int it = 0; it < ITER; ++it) {
        int nb = (blockIdx.x * ITER + it) * 64;
        __syncthreads();
        if constexpr (sizeof(TIN) == 2) {
            // fp16 input: read __half2 pairs (FIN even)
            for (int p = t; p < 64 * FIN / 2; p += 256) {
                int nn = (2 * p) / FIN, kk = (2 * p) % FIN;
                __half2 v = ((const __half2*)in)[(size_t)(nb + nn) * (FIN / 2) + (kk >> 1)];
                Xl[kk * XS + nn] = __low2float(v);
                Xl[(kk + 1) * XS + nn] = __high2float(v);
            }
        } else {
            for (int i = t; i < 64 * FIN; i += 256) {
                int nn = i / FIN, kk = i % FIN;
                Xl[kk * XS + nn] = (float)in[(size_t)(nb + nn) * FIN + kk];
            }
        }
        __syncthreads();

        float acc[4][TF];
#pragma unroll
        for (int i = 0; i < 4; i++)
#pragma unroll
            for (int j = 0; j < TF; j++) acc[i][j] = 0.f;

#pragma unroll 2
        for (int k = 0; k < FIN; ++k) {
            float4 xv = *(const float4*)&Xl[k * XS + ng * 4];
            float wv[TF];
#pragma unroll
            for (int j4 = 0; j4 < TF; j4 += 4) {
                float4 w4 = *(const float4*)&Wl[k * F + f0 + j4];
                wv[j4] = w4.x; wv[j4 + 1] = w4.y; wv[j4 + 2] = w4.z; wv[j4 + 3] = w4.w;
            }
            const float xs[4] = {xv.x, xv.y, xv.z, xv.w};
#pragma unroll
            for (int i = 0; i < 4; i++)
#pragma unroll
                for (int j = 0; j < TF; j++) acc[i][j] = fmaf(xs[i], wv[j], acc[i][j]);
        }

        // epilogue: h (fp16) + fused alpha projections
#pragma unroll
        for (int i = 0; i < 4; i++) {
            int n = nb + ng * 4 + i;
            __half hv[TF];
            float ps = 0.f, pd = 0.f;
#pragma unroll
            for (int j = 0; j < TF; j++) {
                hv[j] = __float2half(acc[i][j]);
                ps = fmaf(acc[i][j], asf[j], ps);
                pd = fmaf(acc[i][j], adf[j], pd);
            }
            if constexpr (TF == 4) {
                *(uint2*)(h + (size_t)n * F + f0) = *(uint2*)hv;
            } else {
                *(uint4*)(h + (size_t)n * F + f0) = *(uint4*)hv;
            }
            ps += __shfl_xor(ps, 1);
            pd += __shfl_xor(pd, 1);
            ps += __shfl_xor(ps, 2);
            pd += __shfl_xor(pd, 2);
            if constexpr (H == 1) {
                ps += __shfl_xor(ps, 4);
                pd += __shfl_xor(pd, 4);
                ps += __shfl_xor(ps, 8);
                pd += __shfl_xor(pd, 8);
                if (tfg == 0) {
                    alpha_s[n] = ps;
                    alpha_d[n] = pd;
                }
            } else {
                if ((tfg & 3) == 0) {
                    alpha_s[(size_t)n * H + (tfg >> 2)] = ps;
                    alpha_d[(size_t)n * H + (tfg >> 2)] = pd;
                }
            }
        }
    }
}

// ---------------- per-node softmax + aggregation (2 nodes / wave, 8 nodes / block) ----------------
// fp16 output activations. Phase 1 on half-waves; phase 2: uint4 gathers, unroll 8.
template <int H, int C, bool FINAL>
__global__ __launch_bounds__(256) void k_aggregate(
    const __half* __restrict__ h, const float* __restrict__ asrc, const float* __restrict__ adst,
    const int* __restrict__ rowptr, const unsigned int* __restrict__ ep,
    const float* __restrict__ ceb, const float* __restrict__ b,
    const float* __restrict__ bn_g, const float* __restrict__ bn_b,
    const float* __restrict__ bn_rm, const float* __restrict__ bn_rv,
    __half* __restrict__ out) {
    constexpr int F = H * C;
    constexpr bool P2 = (F > 64);
    constexpr int FSB = P2 ? 256 : 128;  // h row stride in BYTES
    __shared__ float lds_att[4][64 * H];
    __shared__ int lds_off[4][64];

    int wid = threadIdx.x >> 6;
    int lane = threadIdx.x & 63;
    int half = lane >> 5;
    int hl = lane & 31;
    int n = blockIdx.x * 8 + wid * 2 + half;
    int r0 = rowptr[n];
    int r1 = rowptr[n + 1];
    int deg = r1 - r0;

    float ce[H], ad[H];
#pragma unroll
    for (int hh = 0; hh < H; hh++) ce[hh] = ceb[hh];
    if constexpr (H == 4) {
        float4 adv = ((const float4*)adst)[n];
        ad[0] = adv.x; ad[1] = adv.y; ad[2] = adv.z; ad[3] = adv.w;
    } else {
        ad[0] = adst[n];
    }

    // ---- phase 1: one edge per lane (32 lanes per node) ----
    bool val = hl < deg;
    int s_l = 0;
    float w_l = 0.f;
    if (val) ep_unpack(ep[r0 + hl], s_l, w_l);
    float ex_l[H], psum[H];
    if constexpr (H == 4) {
        if (val) {
            float4 v4 = ((const float4*)asrc)[s_l];
            ex_l[0] = __expf(fminf(lrelu(v4.x + ad[0] + w_l * ce[0], 0.2f), 80.f));
            ex_l[1] = __expf(fminf(lrelu(v4.y + ad[1] + w_l * ce[1], 0.2f), 80.f));
            ex_l[2] = __expf(fminf(lrelu(v4.z + ad[2] + w_l * ce[2], 0.2f), 80.f));
            ex_l[3] = __expf(fminf(lrelu(v4.w + ad[3] + w_l * ce[3], 0.2f), 80.f));
        } else {
            ex_l[0] = ex_l[1] = ex_l[2] = ex_l[3] = 0.f;
        }
    } else {
        ex_l[0] = val ? __expf(fminf(lrelu(asrc[s_l] + ad[0] + w_l * ce[0], 0.2f), 80.f)) : 0.f;
    }
#pragma unroll
    for (int hh = 0; hh < H; hh++) psum[hh] = ex_l[hh];
    // overflow edges (deg > 32, rare): add into denom (per half-wave)
    for (int r = r0 + 32 + hl; r < r1; r += 32) {
        int s;
        float w;
        ep_unpack(ep[r], s, w);
        if constexpr (H == 4) {
            float4 v4 = ((const float4*)asrc)[s];
            psum[0] += __expf(fminf(lrelu(v4.x + ad[0] + w * ce[0], 0.2f), 80.f));
            psum[1] += __expf(fminf(lrelu(v4.y + ad[1] + w * ce[1], 0.2f), 80.f));
            psum[2] += __expf(fminf(lrelu(v4.z + ad[2] + w * ce[2], 0.2f), 80.f));
            psum[3] += __expf(fminf(lrelu(v4.w + ad[3] + w * ce[3], 0.2f), 80.f));
        } else {
            psum[0] += __expf(fminf(lrelu(asrc[s] + ad[0] + w * ce[0], 0.2f), 80.f));
        }
    }
    float rden[H];
#pragma unroll
    for (int hh = 0; hh < H; hh++) {
        float v = psum[hh];
#pragma unroll
        for (int off = 16; off >= 1; off >>= 1) v += __shfl_xor(v, off);  // half-wave reduce
        rden[hh] = 1.f / (v + 1e-16f);
    }

    // stage att = ex/den and row byte-offset in LDS (32 slots per node, all initialized)
    lds_off[wid][lane] = s_l * FSB;
#pragma unroll
    for (int hh = 0; hh < H; hh++) lds_att[wid][lane * H + hh] = ex_l[hh] * rden[hh];
    __syncthreads();

    int jn = deg < 32 ? deg : 32;
    int base = half * 32;
    const char* hb = (const char*)h;

    if constexpr (P2) {
        // F=128: 16 lanes/edge, 8 features (uint4) per lane, 2 edges/iter per node
        int flane = hl & 15;
        int grp = hl >> 4;
        int f0 = 8 * flane;
        int hsel = f0 >> 5;  // C=32
        float a[8];
#pragma unroll
        for (int i = 0; i < 8; i++) a[i] = 0.f;
#pragma unroll 8
        for (int j = 0; j < jn; j += 2) {
            int je = base + j + grp;
            int off = lds_off[wid][je];
            float att = lds_att[wid][je * H + hsel];
            uint4 p = *(const uint4*)(hb + (size_t)(off + flane * 16));
            const __half2* hp = (const __half2*)&p;
#pragma unroll
            for (int i = 0; i < 4; i++) {
                a[2 * i] = fmaf(__low2float(hp[i]), att, a[2 * i]);
                a[2 * i + 1] = fmaf(__high2float(hp[i]), att, a[2 * i + 1]);
            }
        }
        if (deg > 32) {  // rare
            float rdensel = sel_h<H>(rden, hsel);
            for (int r = r0 + 32; r < r1; ++r) {
                unsigned int u = ep[r];
                int s;
                float w;
                ep_unpack(u, s, w);
                float4 v4 = ((const float4*)asrc)[s];
                float aA[4];
                aA[0] = fminf(lrelu(v4.x + ad[0] + w * ce[0], 0.2f), 80.f);
                aA[1] = fminf(lrelu(v4.y + ad[1] + w * ce[1], 0.2f), 80.f);
                aA[2] = fminf(lrelu(v4.z + ad[2] + w * ce[2], 0.2f), 80.f);
                aA[3] = fminf(lrelu(v4.w + ad[3] + w * ce[3], 0.2f), 80.f);
                float att = __expf(sel_h<H>(aA, hsel)) * rdensel;
                att = (grp == 0) ? att : 0.f;
                uint4 p = *(const uint4*)(hb + (size_t)(s * FSB + flane * 16));
                const __half2* hp = (const __half2*)&p;
#pragma unroll
                for (int i = 0; i < 4; i++) {
                    a[2 * i] = fmaf(__low2float(hp[i]), att, a[2 * i]);
                    a[2 * i + 1] = fmaf(__high2float(hp[i]), att, a[2 * i + 1]);
                }
            }
        }
#pragma unroll
        for (int i = 0; i < 8; i++) a[i] += __shfl_xor(a[i], 16);
        if (hl < 16) {
            __half ho[8];
#pragma unroll
            for (int i = 0; i < 8; i++) ho[i] = __float2half(lrelu(a[i] + b[f0 + i], 0.01f));
            ((uint4*)out)[(size_t)n * 16 + flane] = *(uint4*)ho;
        }
    } else {
        // F<=64: 8 lanes/edge, 8 features (uint4) per lane, 4 edges/iter per node
        int flane = hl & 7;
        int grp = hl >> 3;
        int f0 = 8 * flane;
        int hsel = (H == 1) ? 0 : (f0 >> 4);  // C=16
        float a[8];
#pragma unroll
        for (int i = 0; i < 8; i++) a[i] = 0.f;
#pragma unroll 8
        for (int j = 0; j < jn; j += 4) {
            int je = base + j + grp;
            int off = lds_off[wid][je];
            float att = lds_att[wid][je * H + hsel];
            uint4 p = *(const uint4*)(hb + (size_t)(off + flane * 16));
            const __half2* hp = (const __half2*)&p;
#pragma unroll
            for (int i = 0; i < 4; i++) {
                a[2 * i] = fmaf(__low2float(hp[i]), att, a[2 * i]);
                a[2 * i + 1] = fmaf(__high2float(hp[i]), att, a[2 * i + 1]);
            }
        }
        if (deg > 32) {  // rare
            float rdensel = sel_h<H>(rden, hsel);
            for (int r = r0 + 32; r < r1; ++r) {
                unsigned int u = ep[r];
                int s;
                float w;
                ep_unpack(u, s, w);
                float aA[H];
                if constexpr (H == 4) {
                    float4 v4 = ((const float4*)asrc)[s];
                    aA[0] = fminf(lrelu(v4.x + ad[0] + w * ce[0], 0.2f), 80.f);
                    aA[1] = fminf(lrelu(v4.y + ad[1] + w * ce[1], 0.2f), 80.f);
                    aA[2] = fminf(lrelu(v4.z + ad[2] + w * ce[2], 0.2f), 80.f);
                    aA[3] = fminf(lrelu(v4.w + ad[3] + w * ce[3], 0.2f), 80.f);
                } else {
                    aA[0] = fminf(lrelu(asrc[s] + ad[0] + w * ce[0], 0.2f), 80.f);
                }
                float att = __expf(sel_h<H>(aA, hsel)) * rdensel;
                att = (grp == 0) ? att : 0.f;
                uint4 p = *(const uint4*)(hb + (size_t)(s * FSB + flane * 16));
                const __half2* hp = (const __half2*)&p;
#pragma unroll
                for (int i = 0; i < 4; i++) {
                    a[2 * i] = fmaf(__low2float(hp[i]), att, a[2 * i]);
                    a[2 * i + 1] = fmaf(__high2float(hp[i]), att, a[2 * i + 1]);
                }
            }
        }
#pragma unroll
        for (int i = 0; i < 8; i++) {
            a[i] += __shfl_xor(a[i], 8);
            a[i] += __shfl_xor(a[i], 16);
        }
        if constexpr (FINAL) {
            if (hl < 7) {
                __half ho[8];
#pragma unroll
                for (int k = 0; k < 8; k++) {
                    int f = f0 + k;
                    float o = 0.f;
                    if (f < 50) {
                        float v = a[k] + b[f];
                        v = (v - bn_rm[f]) * rsqrtf(bn_rv[f] + 1e-5f) * bn_g[f] + bn_b[f];
                        o = lrelu(v, 0.01f);
                    }
                    ho[k] = __float2half(o);
                }
                ((uint4*)out)[(size_t)n * 8 + hl] = *(uint4*)ho;
            }
        } else {
            if (hl < 8) {
                __half ho[8];
#pragma unroll
                for (int i = 0; i < 8; i++) ho[i] = __float2half(lrelu(a[i] + b[f0 + i], 0.01f));
                ((uint4*)out)[(size_t)n * 8 + flane] = *(uint4*)ho;
            }
        }
    }
}

// ---------------- fused graph pooling (sorted batch, binary search) + final MLP ----------------
// One block = 64 graphs. Phase A: 4 waves pool 16 graphs each into LDS (fp16 node feats).
// Phase B: threads 0..63 run the 50->30->20->2 MLP, one graph per thread.
__global__ __launch_bounds__(256) void k_pool_mlp(
    const __half* __restrict__ nodeout, const int* __restrict__ batch,
    const float* __restrict__ Wf1, const float* __restrict__ bf1,
    const float* __restrict__ Wf2, const float* __restrict__ bf2,
    const float* __restrict__ Wf3, const float* __restrict__ bf3,
    float* __restrict__ out) {
    __shared__ float W1[1500], W2[600], W3[40], B1[30], B2[20], B3[2];
    __shared__ float G[64 * 51];
    int t = threadIdx.x;
    for (int i = t; i < 1500; i += 256) W1[i] = Wf1[i];
    for (int i = t; i < 600; i += 256) W2[i] = Wf2[i];
    if (t < 40) W3[t] = Wf3[t];
    if (t < 30) B1[t] = bf1[t];
    if (t < 20) B2[t] = bf2[t];
    if (t < 2) B3[t] = bf3[t];
    int g0 = blockIdx.x * 64;
    int wv = t >> 6, lane = t & 63;
    for (int k = 0; k < 16; ++k) {
        int lg = wv * 16 + k;
        int g = g0 + lg;
        int lo = 0, hi = NN;
        while (lo < hi) {
            int mid = (lo + hi) >> 1;
            if (batch[mid] < g) lo = mid + 1; else hi = mid;
        }
        int s0 = lo;
        hi = NN;
        while (lo < hi) {
            int mid = (lo + hi) >> 1;
            if (batch[mid] < g + 1) lo = mid + 1; else hi = mid;
        }
        int s1 = lo;
        if (lane < 50) {
            float acc = 0.f;
            for (int n = s0; n < s1; ++n) acc += __half2float(nodeout[(size_t)n * 64 + lane]);
            G[lg * 51 + lane] = acc;
        }
    }
    __syncthreads();
    if (t < 64) {
        float gv[50];
#pragma unroll
        for (int i = 0; i < 50; i++) gv[i] = G[t * 51 + i];
        float h1[30];
#pragma unroll
        for (int j = 0; j < 30; j++) {
            float a = B1[j];
#pragma unroll
            for (int i = 0; i < 50; i++) a += gv[i] * W1[i * 30 + j];
            h1[j] = lrelu(a, 0.01f);
        }
        float h2[20];
#pragma unroll
        for (int j = 0; j < 20; j++) {
            float a = B2[j];
#pragma unroll
            for (int i = 0; i < 30; i++) a += h1[i] * W2[i * 20 + j];
            h2[j] = lrelu(a, 0.01f);
        }
        float o0 = B3[0], o1 = B3[1];
#pragma unroll
        for (int i = 0; i < 20; i++) {
            o0 += h2[i] * W3[i * 2];
            o1 += h2[i] * W3[i * 2 + 1];
        }
        ((float2*)out)[g0 + t] = make_float2(o0, o1);
    }
}

extern "C" void kernel_launch(void* const* d_in, const int* in_sizes, int n_in,
                              void* d_out, int out_size, void* d_ws, size_t ws_size,
                              hipStream_t stream) {
    const float* x = (const float*)d_in[0];
    const int* ei = (const int*)d_in[1];
    const float* ew = (const float*)d_in[2];
    const int* batch = (const int*)d_in[3];
    const float* W1 = (const float*)d_in[4];
    const float* as1 = (const float*)d_in[5];
    const float* ad1 = (const float*)d_in[6];
    const float* We1 = (const float*)d_in[7];
    const float* ae1 = (const float*)d_in[8];
    const float* b1 = (const float*)d_in[9];
    const float* W2 = (const float*)d_in[10];
    const float* as2 = (const float*)d_in[11];
    const float* ad2 = (const float*)d_in[12];
    const float* We2 = (const float*)d_in[13];
    const float* ae2 = (const float*)d_in[14];
    const float* b2 = (const float*)d_in[15];
    const float* W3 = (const float*)d_in[16];
    const float* as3 = (const float*)d_in[17];
    const float* ad3 = (const float*)d_in[18];
    const float* We3 = (const float*)d_in[19];
    const float* ae3 = (const float*)d_in[20];
    const float* b3 = (const float*)d_in[21];
    const float* W4 = (const float*)d_in[22];
    const float* as4 = (const float*)d_in[23];
    const float* ad4 = (const float*)d_in[24];
    const float* We4 = (const float*)d_in[25];
    const float* ae4 = (const float*)d_in[26];
    const float* b4 = (const float*)d_in[27];
    const float* bn_g = (const float*)d_in[28];
    const float* bn_b = (const float*)d_in[29];
    const float* bn_rm = (const float*)d_in[30];
    const float* bn_rv = (const float*)d_in[31];
    const float* Wf1 = (const float*)d_in[32];
    const float* bf1 = (const float*)d_in[33];
    const float* Wf2 = (const float*)d_in[34];
    const float* bf2 = (const float*)d_in[35];
    const float* Wf3 = (const float*)d_in[36];
    const float* bf3 = (const float*)d_in[37];
    float* out = (float*)d_out;

    const int* src = ei;
    const int* dst = ei + NE;

    // workspace layout
    char* ws = (char*)d_ws;
    __half* feat = (__half*)ws;       ws += (size_t)NN * 128 * 2;  // 32 MB fp16 activations
    __half* hbuf = (__half*)ws;       ws += (size_t)NN * 128 * 2;  // 32 MB fp16 transformed h
    float* as_buf = (float*)ws;       ws += (size_t)NN * 4 * 4;
    float* ad_buf = (float*)ws;       ws += (size_t)NN * 4 * 4;
    int* cnt = (int*)ws;              ws += (size_t)NN * 4;
    int* rowptr = (int*)ws;           ws += (size_t)(NN + 64) * 4;
    unsigned int* ep = (unsigned int*)ws; ws += (size_t)NE * 4;
    int* part = (int*)ws;             ws += 512 * 4;
    float* ce_buf = (float*)ws;       ws += 64 * 4;
    // rank reuses hbuf (free until layer-1 transform, which runs after scatter)
    int* rank = (int*)hbuf;

    // CSR build + per-layer edge constants
    hipMemsetAsync(cnt, 0, (size_t)NN * 4, stream);
    k_hist<<<NE / 256, 256, 0, stream>>>(dst, cnt, rank);
    k_scan1<<<NN / 256, 256, 0, stream>>>(cnt, rowptr, part);
    k_scan2<<<1, 512, 0, stream>>>(part, We1, ae1, We2, ae2, We3, ae3, We4, ae4, ce_buf);
    k_scan3<<<NN / 256, 256, 0, stream>>>(rowptr, part);
    k_scatter<<<NE / 256, 256, 0, stream>>>(src, dst, ew, rowptr, rank, ep);

    // layer 1: fin=6, H=4, C=16 (F=64)
    k_transform<float, 6, 64, 64, 4, 16, 4><<<NN / 256, 256, 0, stream>>>(x, W1, as1, ad1, hbuf, as_buf, ad_buf);
    k_aggregate<4, 16, false><<<NN / 8, 256, 0, stream>>>(hbuf, as_buf, ad_buf, rowptr, ep, ce_buf,
                                                          b1, nullptr, nullptr, nullptr, nullptr, feat);
    // layer 2: fin=64, H=4, C=32 (F=128)
    k_transform<__half, 64, 128, 128, 4, 32, 4><<<NN / 256, 256, 0, stream>>>(feat, W2, as2, ad2, hbuf, as_buf, ad_buf);
    k_aggregate<4, 32, false><<<NN / 8, 256, 0, stream>>>(hbuf, as_buf, ad_buf, rowptr, ep, ce_buf + 4,
                                                          b2, nullptr, nullptr, nullptr, nullptr, feat);
    // layer 3: fin=128, H=4, C=16 (F=64)
    k_transform<__half, 128, 64, 64, 4, 16, 4><<<NN / 256, 256, 0, stream>>>(feat, W3, as3, ad3, hbuf, as_buf, ad_buf);
    k_aggregate<4, 16, false><<<NN / 8, 256, 0, stream>>>(hbuf, as_buf, ad_buf, rowptr, ep, ce_buf + 8,
                                                          b3, nullptr, nullptr, nullptr, nullptr, feat);
    // layer 4: fin=64, F padded 50->64, H=1, fused bias+BN+lrelu, fp16 per-node out
    k_transform<__half, 64, 64, 50, 1, 50, 4><<<NN / 256, 256, 0, stream>>>(feat, W4, as4, ad4, hbuf, as_buf, ad_buf);
    k_aggregate<1, 50, true><<<NN / 8, 256, 0, stream>>>(hbuf, as_buf, ad_buf, rowptr, ep, ce_buf + 12,
                                                         b4, bn_g, bn_b, bn_rm, bn_rv, feat);
    // fused graph pooling + final MLP
    k_pool_mlp<<<NG / 64, 256, 0, stream>>>(feat, batch, Wf1, bf1, Wf2, bf2, Wf3, bf3, out);
}

// Round 11
// 773.720 us; speedup vs baseline: 1.1255x; 1.1255x over previous
//
#include <hip/hip_runtime.h>
#include <hip/hip_fp16.h>
#include <math.h>

#define NN 131072
#define NE 2097152
#define NG 16384

__device__ __forceinline__ float lrelu(float x, float s) { return fmaxf(x, s * x); }

template <int H>
__device__ __forceinline__ float sel_h(const float* a, int hsel) {
    if constexpr (H == 1) return a[0];
    else return hsel == 0 ? a[0] : hsel == 1 ? a[1] : hsel == 2 ? a[2] : a[3];
}

// ---------------- CSR build ----------------
__global__ void k_hist(const int* __restrict__ dst, int* __restrict__ cnt, int* __restrict__ rank) {
    int e = blockIdx.x * 256 + threadIdx.x;
    rank[e] = atomicAdd(&cnt[dst[e]], 1);
}

__global__ void k_scan1(const int* __restrict__ cnt, int* __restrict__ rowptr, int* __restrict__ part) {
    __shared__ int s[256];
    int t = threadIdx.x;
    int i = blockIdx.x * 256 + t;
    int v = cnt[i];
    s[t] = v;
    __syncthreads();
    for (int off = 1; off < 256; off <<= 1) {
        int x = (t >= off) ? s[t - off] : 0;
        __syncthreads();
        s[t] += x;
        __syncthreads();
    }
    rowptr[i] = s[t] - v;  // exclusive
    if (t == 255) part[blockIdx.x] = s[255];
}

// scan of block partials + per-layer attention-edge constants ce[h] = dot(We[h], ae[h])
__global__ void k_scan2(int* part,
                        const float* __restrict__ We1, const float* __restrict__ ae1,
                        const float* __restrict__ We2, const float* __restrict__ ae2,
                        const float* __restrict__ We3, const float* __restrict__ ae3,
                        const float* __restrict__ We4, const float* __restrict__ ae4,
                        float* __restrict__ ceb) {
    __shared__ int s[512];
    int t = threadIdx.x;
    int v = part[t];
    s[t] = v;
    __syncthreads();
    for (int off = 1; off < 512; off <<= 1) {
        int x = (t >= off) ? s[t - off] : 0;
        __syncthreads();
        s[t] += x;
        __syncthreads();
    }
    part[t] = s[t] - v;  // exclusive
    if (t < 4) {
        float c = 0.f;
        for (int i = 0; i < 16; i++) c += We1[t * 16 + i] * ae1[t * 16 + i];
        ceb[t] = c;
    } else if (t < 8) {
        int h = t - 4;
        float c = 0.f;
        for (int i = 0; i < 32; i++) c += We2[h * 32 + i] * ae2[h * 32 + i];
        ceb[t] = c;
    } else if (t < 12) {
        int h = t - 8;
        float c = 0.f;
        for (int i = 0; i < 16; i++) c += We3[h * 16 + i] * ae3[h * 16 + i];
        ceb[t] = c;
    } else if (t == 12) {
        float c = 0.f;
        for (int i = 0; i < 50; i++) c += We4[i] * ae4[i];
        ceb[t] = c;
    }
}

__global__ void k_scan3(int* __restrict__ rowptr, const int* __restrict__ part) {
    int t = threadIdx.x;
    int i = blockIdx.x * 256 + t;
    rowptr[i] = rowptr[i] + part[blockIdx.x];
    if (i == 0) rowptr[NN] = NE;
}

// scatter edges into dst-sorted order (no atomics), packing (src, ew) into one uint
__global__ void k_scatter(const int* __restrict__ src, const int* __restrict__ dst,
                          const float* __restrict__ ew, const int* __restrict__ rowptr,
                          const int* __restrict__ rank, unsigned int* __restrict__ ep) {
    int e = blockIdx.x * 256 + threadIdx.x;
    int d = dst[e];
    int p = rowptr[d] + rank[e];
    unsigned int s = (unsigned int)src[e];
    unsigned int q = (unsigned int)(ew[e] * 32767.f + 0.5f);
    __builtin_nontemporal_store((s << 15) | (q & 0x7fffu), &ep[p]);
}

__device__ __forceinline__ void ep_unpack(unsigned int u, int& s, float& w) {
    s = (int)(u >> 15);
    w = (float)(u & 0x7fffu) * (1.f / 32767.f);
}

// ---------------- node transform + fused alpha projections (register-tiled GEMM) ----------------
// TIN = float (layer 1 input) or __half (fp16 inter-layer activations).
template <typename TIN, int FIN, int F, int FR, int H, int C, int ITER>
__global__ __launch_bounds__(256) void k_transform(
    const TIN* __restrict__ in, const float* __restrict__ W,
    const float* __restrict__ as_, const float* __restrict__ ad_,
    __half* __restrict__ h, float* __restrict__ alpha_s, float* __restrict__ alpha_d) {
    constexpr int TF = F / 16;   // features per thread
    constexpr int XS = 65;       // Xl row stride (floats)
    __shared__ float Wl[FIN * F];
    __shared__ float Xl[FIN * XS];
    int t = threadIdx.x;
    int tfg = t & 15;   // feature group
    int ng = t >> 4;    // node group (0..15)
    int f0 = tfg * TF;

    for (int i = t; i < FIN * F; i += 256) {
        int ff = i % F;
        Wl[i] = (ff < FR) ? W[(i / F) * FR + ff] : 0.f;
    }
    float asf[TF], adf[TF];
#pragma unroll
    for (int j = 0; j < TF; j++) {
        bool v = (f0 + j) < FR;
        asf[j] = v ? as_[f0 + j] : 0.f;
        adf[j] = v ? ad_[f0 + j] : 0.f;
    }

    for (int it = 0; it < ITER; ++it) {
        int nb = (blockIdx.x * ITER + it) * 64;
        __syncthreads();
        if constexpr (sizeof(TIN) == 2) {
            for (int p = t; p < 64 * FIN / 2; p += 256) {
                int nn = (2 * p) / FIN, kk = (2 * p) % FIN;
                __half2 v = ((const __half2*)in)[(size_t)(nb + nn) * (FIN / 2) + (kk >> 1)];
                Xl[kk * XS + nn] = __low2float(v);
                Xl[(kk + 1) * XS + nn] = __high2float(v);
            }
        } else {
            for (int i = t; i < 64 * FIN; i += 256) {
                int nn = i / FIN, kk = i % FIN;
                Xl[kk * XS + nn] = (float)in[(size_t)(nb + nn) * FIN + kk];
            }
        }
        __syncthreads();

        float acc[4][TF];
#pragma unroll
        for (int i = 0; i < 4; i++)
#pragma unroll
            for (int j = 0; j < TF; j++) acc[i][j] = 0.f;

#pragma unroll 2
        for (int k = 0; k < FIN; ++k) {
            float4 xv = *(const float4*)&Xl[k * XS + ng * 4];
            float wv[TF];
#pragma unroll
            for (int j4 = 0; j4 < TF; j4 += 4) {
                float4 w4 = *(const float4*)&Wl[k * F + f0 + j4];
                wv[j4] = w4.x; wv[j4 + 1] = w4.y; wv[j4 + 2] = w4.z; wv[j4 + 3] = w4.w;
            }
            const float xs[4] = {xv.x, xv.y, xv.z, xv.w};
#pragma unroll
            for (int i = 0; i < 4; i++)
#pragma unroll
                for (int j = 0; j < TF; j++) acc[i][j] = fmaf(xs[i], wv[j], acc[i][j]);
        }

        // epilogue: h (fp16) + fused alpha projections
#pragma unroll
        for (int i = 0; i < 4; i++) {
            int n = nb + ng * 4 + i;
            __half hv[TF];
            float ps = 0.f, pd = 0.f;
#pragma unroll
            for (int j = 0; j < TF; j++) {
                hv[j] = __float2half(acc[i][j]);
                ps = fmaf(acc[i][j], asf[j], ps);
                pd = fmaf(acc[i][j], adf[j], pd);
            }
            if constexpr (TF == 4) {
                *(uint2*)(h + (size_t)n * F + f0) = *(uint2*)hv;
            } else {
                *(uint4*)(h + (size_t)n * F + f0) = *(uint4*)hv;
            }
            ps += __shfl_xor(ps, 1);
            pd += __shfl_xor(pd, 1);
            ps += __shfl_xor(ps, 2);
            pd += __shfl_xor(pd, 2);
            if constexpr (H == 1) {
                ps += __shfl_xor(ps, 4);
                pd += __shfl_xor(pd, 4);
                ps += __shfl_xor(ps, 8);
                pd += __shfl_xor(pd, 8);
                if (tfg == 0) {
                    alpha_s[n] = ps;
                    alpha_d[n] = pd;
                }
            } else {
                if ((tfg & 3) == 0) {
                    alpha_s[(size_t)n * H + (tfg >> 2)] = ps;
                    alpha_d[(size_t)n * H + (tfg >> 2)] = pd;
                }
            }
        }
    }
}

// ---------------- per-node softmax + aggregation (2 nodes / wave, 8 nodes / block) ----------------
template <int H, int C, bool FINAL>
__global__ __launch_bounds__(256) void k_aggregate(
    const __half* __restrict__ h, const float* __restrict__ asrc, const float* __restrict__ adst,
    const int* __restrict__ rowptr, const unsigned int* __restrict__ ep,
    const float* __restrict__ ceb, const float* __restrict__ b,
    const float* __restrict__ bn_g, const float* __restrict__ bn_b,
    const float* __restrict__ bn_rm, const float* __restrict__ bn_rv,
    __half* __restrict__ out) {
    constexpr int F = H * C;
    constexpr bool P2 = (F > 64);
    constexpr int FSB = P2 ? 256 : 128;  // h row stride in BYTES
    __shared__ float lds_att[4][64 * H];
    __shared__ int lds_off[4][64];

    int wid = threadIdx.x >> 6;
    int lane = threadIdx.x & 63;
    int half = lane >> 5;
    int hl = lane & 31;
    int n = blockIdx.x * 8 + wid * 2 + half;
    int r0 = rowptr[n];
    int r1 = rowptr[n + 1];
    int deg = r1 - r0;

    float ce[H], ad[H];
#pragma unroll
    for (int hh = 0; hh < H; hh++) ce[hh] = ceb[hh];
    if constexpr (H == 4) {
        float4 adv = ((const float4*)adst)[n];
        ad[0] = adv.x; ad[1] = adv.y; ad[2] = adv.z; ad[3] = adv.w;
    } else {
        ad[0] = adst[n];
    }

    // ---- phase 1: one edge per lane (32 lanes per node) ----
    bool val = hl < deg;
    int s_l = 0;
    float w_l = 0.f;
    if (val) ep_unpack(ep[r0 + hl], s_l, w_l);
    float ex_l[H], psum[H];
    if constexpr (H == 4) {
        if (val) {
            float4 v4 = ((const float4*)asrc)[s_l];
            ex_l[0] = __expf(fminf(lrelu(v4.x + ad[0] + w_l * ce[0], 0.2f), 80.f));
            ex_l[1] = __expf(fminf(lrelu(v4.y + ad[1] + w_l * ce[1], 0.2f), 80.f));
            ex_l[2] = __expf(fminf(lrelu(v4.z + ad[2] + w_l * ce[2], 0.2f), 80.f));
            ex_l[3] = __expf(fminf(lrelu(v4.w + ad[3] + w_l * ce[3], 0.2f), 80.f));
        } else {
            ex_l[0] = ex_l[1] = ex_l[2] = ex_l[3] = 0.f;
        }
    } else {
        ex_l[0] = val ? __expf(fminf(lrelu(asrc[s_l] + ad[0] + w_l * ce[0], 0.2f), 80.f)) : 0.f;
    }
#pragma unroll
    for (int hh = 0; hh < H; hh++) psum[hh] = ex_l[hh];
    // overflow edges (deg > 32, rare): add into denom (per half-wave)
    for (int r = r0 + 32 + hl; r < r1; r += 32) {
        int s;
        float w;
        ep_unpack(ep[r], s, w);
        if constexpr (H == 4) {
            float4 v4 = ((const float4*)asrc)[s];
            psum[0] += __expf(fminf(lrelu(v4.x + ad[0] + w * ce[0], 0.2f), 80.f));
            psum[1] += __expf(fminf(lrelu(v4.y + ad[1] + w * ce[1], 0.2f), 80.f));
            psum[2] += __expf(fminf(lrelu(v4.z + ad[2] + w * ce[2], 0.2f), 80.f));
            psum[3] += __expf(fminf(lrelu(v4.w + ad[3] + w * ce[3], 0.2f), 80.f));
        } else {
            psum[0] += __expf(fminf(lrelu(asrc[s] + ad[0] + w * ce[0], 0.2f), 80.f));
        }
    }
    float rden[H];
#pragma unroll
    for (int hh = 0; hh < H; hh++) {
        float v = psum[hh];
#pragma unroll
        for (int off = 16; off >= 1; off >>= 1) v += __shfl_xor(v, off);  // half-wave reduce
        rden[hh] = 1.f / (v + 1e-16f);
    }

    // stage att = ex/den and row byte-offset in LDS (32 slots per node, all initialized)
    lds_off[wid][lane] = s_l * FSB;
#pragma unroll
    for (int hh = 0; hh < H; hh++) lds_att[wid][lane * H + hh] = ex_l[hh] * rden[hh];
    __syncthreads();

    int jn = deg < 32 ? deg : 32;
    int base = half * 32;
    const char* hb = (const char*)h;

    if constexpr (P2) {
        // F=128: 16 lanes/edge, 8 features (uint4) per lane, 2 edges/iter per node
        int flane = hl & 15;
        int grp = hl >> 4;
        int f0 = 8 * flane;
        int hsel = f0 >> 5;  // C=32
        float a[8];
#pragma unroll
        for (int i = 0; i < 8; i++) a[i] = 0.f;
#pragma unroll 8
        for (int j = 0; j < jn; j += 2) {
            int je = base + j + grp;
            int off = lds_off[wid][je];
            float att = lds_att[wid][je * H + hsel];
            uint4 p = *(const uint4*)(hb + (size_t)(off + flane * 16));
            const __half2* hp = (const __half2*)&p;
#pragma unroll
            for (int i = 0; i < 4; i++) {
                a[2 * i] = fmaf(__low2float(hp[i]), att, a[2 * i]);
                a[2 * i + 1] = fmaf(__high2float(hp[i]), att, a[2 * i + 1]);
            }
        }
        if (deg > 32) {  // rare
            float rdensel = sel_h<H>(rden, hsel);
            for (int r = r0 + 32; r < r1; ++r) {
                unsigned int u = ep[r];
                int s;
                float w;
                ep_unpack(u, s, w);
                float4 v4 = ((const float4*)asrc)[s];
                float aA[4];
                aA[0] = fminf(lrelu(v4.x + ad[0] + w * ce[0], 0.2f), 80.f);
                aA[1] = fminf(lrelu(v4.y + ad[1] + w * ce[1], 0.2f), 80.f);
                aA[2] = fminf(lrelu(v4.z + ad[2] + w * ce[2], 0.2f), 80.f);
                aA[3] = fminf(lrelu(v4.w + ad[3] + w * ce[3], 0.2f), 80.f);
                float att = __expf(sel_h<H>(aA, hsel)) * rdensel;
                att = (grp == 0) ? att : 0.f;
                uint4 p = *(const uint4*)(hb + (size_t)(s * FSB + flane * 16));
                const __half2* hp = (const __half2*)&p;
#pragma unroll
                for (int i = 0; i < 4; i++) {
                    a[2 * i] = fmaf(__low2float(hp[i]), att, a[2 * i]);
                    a[2 * i + 1] = fmaf(__high2float(hp[i]), att, a[2 * i + 1]);
                }
            }
        }
#pragma unroll
        for (int i = 0; i < 8; i++) a[i] += __shfl_xor(a[i], 16);
        if (hl < 16) {
            __half ho[8];
#pragma unroll
            for (int i = 0; i < 8; i++) ho[i] = __float2half(lrelu(a[i] + b[f0 + i], 0.01f));
            ((uint4*)out)[(size_t)n * 16 + flane] = *(uint4*)ho;
        }
    } else {
        // F<=64: 8 lanes/edge, 8 features (uint4) per lane, 4 edges/iter per node
        int flane = hl & 7;
        int grp = hl >> 3;
        int f0 = 8 * flane;
        int hsel = (H == 1) ? 0 : (f0 >> 4);  // C=16
        float a[8];
#pragma unroll
        for (int i = 0; i < 8; i++) a[i] = 0.f;
#pragma unroll 8
        for (int j = 0; j < jn; j += 4) {
            int je = base + j + grp;
            int off = lds_off[wid][je];
            float att = lds_att[wid][je * H + hsel];
            uint4 p = *(const uint4*)(hb + (size_t)(off + flane * 16));
            const __half2* hp = (const __half2*)&p;
#pragma unroll
            for (int i = 0; i < 4; i++) {
                a[2 * i] = fmaf(__low2float(hp[i]), att, a[2 * i]);
                a[2 * i + 1] = fmaf(__high2float(hp[i]), att, a[2 * i + 1]);
            }
        }
        if (deg > 32) {  // rare
            float rdensel = sel_h<H>(rden, hsel);
            for (int r = r0 + 32; r < r1; ++r) {
                unsigned int u = ep[r];
                int s;
                float w;
                ep_unpack(u, s, w);
                float aA[H];
                if constexpr (H == 4) {
                    float4 v4 = ((const float4*)asrc)[s];
                    aA[0] = fminf(lrelu(v4.x + ad[0] + w * ce[0], 0.2f), 80.f);
                    aA[1] = fminf(lrelu(v4.y + ad[1] + w * ce[1], 0.2f), 80.f);
                    aA[2] = fminf(lrelu(v4.z + ad[2] + w * ce[2], 0.2f), 80.f);
                    aA[3] = fminf(lrelu(v4.w + ad[3] + w * ce[3], 0.2f), 80.f);
                } else {
                    aA[0] = fminf(lrelu(asrc[s] + ad[0] + w * ce[0], 0.2f), 80.f);
                }
                float att = __expf(sel_h<H>(aA, hsel)) * rdensel;
                att = (grp == 0) ? att : 0.f;
                uint4 p = *(const uint4*)(hb + (size_t)(s * FSB + flane * 16));
                const __half2* hp = (const __half2*)&p;
#pragma unroll
                for (int i = 0; i < 4; i++) {
                    a[2 * i] = fmaf(__low2float(hp[i]), att, a[2 * i]);
                    a[2 * i + 1] = fmaf(__high2float(hp[i]), att, a[2 * i + 1]);
                }
            }
        }
#pragma unroll
        for (int i = 0; i < 8; i++) {
            a[i] += __shfl_xor(a[i], 8);
            a[i] += __shfl_xor(a[i], 16);
        }
        if constexpr (FINAL) {
            if (hl < 7) {
                __half ho[8];
#pragma unroll
                for (int k = 0; k < 8; k++) {
                    int f = f0 + k;
                    float o = 0.f;
                    if (f < 50) {
                        float v = a[k] + b[f];
                        v = (v - bn_rm[f]) * rsqrtf(bn_rv[f] + 1e-5f) * bn_g[f] + bn_b[f];
                        o = lrelu(v, 0.01f);
                    }
                    ho[k] = __float2half(o);
                }
                ((uint4*)out)[(size_t)n * 8 + hl] = *(uint4*)ho;
            }
        } else {
            if (hl < 8) {
                __half ho[8];
#pragma unroll
                for (int i = 0; i < 8; i++) ho[i] = __float2half(lrelu(a[i] + b[f0 + i], 0.01f));
                ((uint4*)out)[(size_t)n * 8 + flane] = *(uint4*)ho;
            }
        }
    }
}

// ---------------- graph pooling: one wave/graph, sorted batch (binary search), fp16 reads ----------------
__global__ __launch_bounds__(256) void k_pool(const __half* __restrict__ nodeout, const int* __restrict__ batch,
                                              float* __restrict__ gbuf) {
    int wid = threadIdx.x >> 6;
    int lane = threadIdx.x & 63;
    int g = blockIdx.x * 4 + wid;
    int lo = 0, hi = NN;
    while (lo < hi) {
        int mid = (lo + hi) >> 1;
        if (batch[mid] < g) lo = mid + 1; else hi = mid;
    }
    int s0 = lo;
    hi = NN;
    while (lo < hi) {
        int mid = (lo + hi) >> 1;
        if (batch[mid] < g + 1) lo = mid + 1; else hi = mid;
    }
    int s1 = lo;
    if (lane < 50) {
        float acc = 0.f;
        for (int n = s0; n < s1; ++n) acc += __half2float(nodeout[(size_t)n * 64 + lane]);
        gbuf[(size_t)g * 50 + lane] = acc;
    }
}

// ---------------- final MLP over graphs: 64 threads/block, 1 graph/thread, LDS-staged ----------------
__global__ __launch_bounds__(64) void k_mlp(const float* __restrict__ gbuf,
                      const float* __restrict__ Wf1, const float* __restrict__ bf1,
                      const float* __restrict__ Wf2, const float* __restrict__ bf2,
                      const float* __restrict__ Wf3, const float* __restrict__ bf3,
                      float* __restrict__ out) {
    __shared__ float W1[1500], W2[600], W3[40], B1[30], B2[20], B3[2];
    __shared__ float G[64 * 50];
    int t = threadIdx.x;
    for (int i = t; i < 1500; i += 64) W1[i] = Wf1[i];
    for (int i = t; i < 600; i += 64) W2[i] = Wf2[i];
    if (t < 40) W3[t] = Wf3[t];
    if (t < 30) B1[t] = bf1[t];
    if (t < 20) B2[t] = bf2[t];
    if (t < 2) B3[t] = bf3[t];
    int g0 = blockIdx.x * 64;
    for (int i = t; i < 64 * 50; i += 64) G[i] = gbuf[(size_t)g0 * 50 + i];
    __syncthreads();
    float gv[50];
#pragma unroll
    for (int i = 0; i < 50; i++) gv[i] = G[t * 50 + i];
    float h1[30];
#pragma unroll
    for (int j = 0; j < 30; j++) {
        float a = B1[j];
#pragma unroll
        for (int i = 0; i < 50; i++) a += gv[i] * W1[i * 30 + j];
        h1[j] = lrelu(a, 0.01f);
    }
    float h2[20];
#pragma unroll
    for (int j = 0; j < 20; j++) {
        float a = B2[j];
#pragma unroll
        for (int i = 0; i < 30; i++) a += h1[i] * W2[i * 20 + j];
        h2[j] = lrelu(a, 0.01f);
    }
    int g = g0 + t;
    float o0 = B3[0], o1 = B3[1];
#pragma unroll
    for (int i = 0; i < 20; i++) {
        o0 += h2[i] * W3[i * 2];
        o1 += h2[i] * W3[i * 2 + 1];
    }
    ((float2*)out)[g] = make_float2(o0, o1);
}

extern "C" void kernel_launch(void* const* d_in, const int* in_sizes, int n_in,
                              void* d_out, int out_size, void* d_ws, size_t ws_size,
                              hipStream_t stream) {
    const float* x = (const float*)d_in[0];
    const int* ei = (const int*)d_in[1];
    const float* ew = (const float*)d_in[2];
    const int* batch = (const int*)d_in[3];
    const float* W1 = (const float*)d_in[4];
    const float* as1 = (const float*)d_in[5];
    const float* ad1 = (const float*)d_in[6];
    const float* We1 = (const float*)d_in[7];
    const float* ae1 = (const float*)d_in[8];
    const float* b1 = (const float*)d_in[9];
    const float* W2 = (const float*)d_in[10];
    const float* as2 = (const float*)d_in[11];
    const float* ad2 = (const float*)d_in[12];
    const float* We2 = (const float*)d_in[13];
    const float* ae2 = (const float*)d_in[14];
    const float* b2 = (const float*)d_in[15];
    const float* W3 = (const float*)d_in[16];
    const float* as3 = (const float*)d_in[17];
    const float* ad3 = (const float*)d_in[18];
    const float* We3 = (const float*)d_in[19];
    const float* ae3 = (const float*)d_in[20];
    const float* b3 = (const float*)d_in[21];
    const float* W4 = (const float*)d_in[22];
    const float* as4 = (const float*)d_in[23];
    const float* ad4 = (const float*)d_in[24];
    const float* We4 = (const float*)d_in[25];
    const float* ae4 = (const float*)d_in[26];
    const float* b4 = (const float*)d_in[27];
    const float* bn_g = (const float*)d_in[28];
    const float* bn_b = (const float*)d_in[29];
    const float* bn_rm = (const float*)d_in[30];
    const float* bn_rv = (const float*)d_in[31];
    const float* Wf1 = (const float*)d_in[32];
    const float* bf1 = (const float*)d_in[33];
    const float* Wf2 = (const float*)d_in[34];
    const float* bf2 = (const float*)d_in[35];
    const float* Wf3 = (const float*)d_in[36];
    const float* bf3 = (const float*)d_in[37];
    float* out = (float*)d_out;

    const int* src = ei;
    const int* dst = ei + NE;

    // workspace layout
    char* ws = (char*)d_ws;
    __half* feat = (__half*)ws;       ws += (size_t)NN * 128 * 2;  // 32 MB fp16 activations
    __half* hbuf = (__half*)ws;       ws += (size_t)NN * 128 * 2;  // 32 MB fp16 transformed h
    float* as_buf = (float*)ws;       ws += (size_t)NN * 4 * 4;
    float* ad_buf = (float*)ws;       ws += (size_t)NN * 4 * 4;
    int* cnt = (int*)ws;              ws += (size_t)NN * 4;
    int* rowptr = (int*)ws;           ws += (size_t)(NN + 64) * 4;
    unsigned int* ep = (unsigned int*)ws; ws += (size_t)NE * 4;
    int* part = (int*)ws;             ws += 512 * 4;
    float* ce_buf = (float*)ws;       ws += 64 * 4;
    float* gbuf = (float*)ws;         ws += (size_t)NG * 50 * 4;
    // rank reuses hbuf (free until layer-1 transform, which runs after scatter)
    int* rank = (int*)hbuf;

    // CSR build + per-layer edge constants
    hipMemsetAsync(cnt, 0, (size_t)NN * 4, stream);
    k_hist<<<NE / 256, 256, 0, stream>>>(dst, cnt, rank);
    k_scan1<<<NN / 256, 256, 0, stream>>>(cnt, rowptr, part);
    k_scan2<<<1, 512, 0, stream>>>(part, We1, ae1, We2, ae2, We3, ae3, We4, ae4, ce_buf);
    k_scan3<<<NN / 256, 256, 0, stream>>>(rowptr, part);
    k_scatter<<<NE / 256, 256, 0, stream>>>(src, dst, ew, rowptr, rank, ep);

    // layer 1: fin=6, H=4, C=16 (F=64)
    k_transform<float, 6, 64, 64, 4, 16, 4><<<NN / 256, 256, 0, stream>>>(x, W1, as1, ad1, hbuf, as_buf, ad_buf);
    k_aggregate<4, 16, false><<<NN / 8, 256, 0, stream>>>(hbuf, as_buf, ad_buf, rowptr, ep, ce_buf,
                                                          b1, nullptr, nullptr, nullptr, nullptr, feat);
    // layer 2: fin=64, H=4, C=32 (F=128)
    k_transform<__half, 64, 128, 128, 4, 32, 4><<<NN / 256, 256, 0, stream>>>(feat, W2, as2, ad2, hbuf, as_buf, ad_buf);
    k_aggregate<4, 32, false><<<NN / 8, 256, 0, stream>>>(hbuf, as_buf, ad_buf, rowptr, ep, ce_buf + 4,
                                                          b2, nullptr, nullptr, nullptr, nullptr, feat);
    // layer 3: fin=128, H=4, C=16 (F=64)
    k_transform<__half, 128, 64, 64, 4, 16, 4><<<NN / 256, 256, 0, stream>>>(feat, W3, as3, ad3, hbuf, as_buf, ad_buf);
    k_aggregate<4, 16, false><<<NN / 8, 256, 0, stream>>>(hbuf, as_buf, ad_buf, rowptr, ep, ce_buf + 8,
                                                          b3, nullptr, nullptr, nullptr, nullptr, feat);
    // layer 4: fin=64, F padded 50->64, H=1, fused bias+BN+lrelu, fp16 per-node out
    k_transform<__half, 64, 64, 50, 1, 50, 4><<<NN / 256, 256, 0, stream>>>(feat, W4, as4, ad4, hbuf, as_buf, ad_buf);
    k_aggregate<1, 50, true><<<NN / 8, 256, 0, stream>>>(hbuf, as_buf, ad_buf, rowptr, ep, ce_buf + 12,
                                                         b4, bn_g, bn_b, bn_rm, bn_rv, feat);
    // graph pooling + final MLP
    k_pool<<<NG / 4, 256, 0, stream>>>(feat, batch, gbuf);
    k_mlp<<<NG / 64, 64, 0, stream>>>(gbuf, Wf1, bf1, Wf2, bf2, Wf3, bf3, out);
}

// Round 12
// 766.180 us; speedup vs baseline: 1.1366x; 1.0098x over previous
//
#include <hip/hip_runtime.h>
#include <hip/hip_fp16.h>
#include <math.h>

#define NN 131072
#define NE 2097152
#define NG 16384

__device__ __forceinline__ float lrelu(float x, float s) { return fmaxf(x, s * x); }

template <int H>
__device__ __forceinline__ float sel_h(const float* a, int hsel) {
    if constexpr (H == 1) return a[0];
    else return hsel == 0 ? a[0] : hsel == 1 ? a[1] : hsel == 2 ? a[2] : a[3];
}

// ---------------- CSR build ----------------
// hist captures each edge's rank within its dst bucket packed with dst: rank<<17 | dst
__global__ void k_hist(const int* __restrict__ dst, int* __restrict__ cnt, unsigned int* __restrict__ rkd) {
    int e = blockIdx.x * 256 + threadIdx.x;
    int d = dst[e];
    unsigned int r = (unsigned int)atomicAdd(&cnt[d], 1);
    rkd[e] = (r << 17) | (unsigned int)d;
}

__global__ void k_scan1(const int* __restrict__ cnt, int* __restrict__ rowptr, int* __restrict__ part) {
    __shared__ int s[256];
    int t = threadIdx.x;
    int i = blockIdx.x * 256 + t;
    int v = cnt[i];
    s[t] = v;
    __syncthreads();
    for (int off = 1; off < 256; off <<= 1) {
        int x = (t >= off) ? s[t - off] : 0;
        __syncthreads();
        s[t] += x;
        __syncthreads();
    }
    rowptr[i] = s[t] - v;  // exclusive
    if (t == 255) part[blockIdx.x] = s[255];
}

// scan of block partials + per-layer attention-edge constants ce[h] = dot(We[h], ae[h])
__global__ void k_scan2(int* part,
                        const float* __restrict__ We1, const float* __restrict__ ae1,
                        const float* __restrict__ We2, const float* __restrict__ ae2,
                        const float* __restrict__ We3, const float* __restrict__ ae3,
                        const float* __restrict__ We4, const float* __restrict__ ae4,
                        float* __restrict__ ceb) {
    __shared__ int s[512];
    int t = threadIdx.x;
    int v = part[t];
    s[t] = v;
    __syncthreads();
    for (int off = 1; off < 512; off <<= 1) {
        int x = (t >= off) ? s[t - off] : 0;
        __syncthreads();
        s[t] += x;
        __syncthreads();
    }
    part[t] = s[t] - v;  // exclusive
    if (t < 4) {
        float c = 0.f;
        for (int i = 0; i < 16; i++) c += We1[t * 16 + i] * ae1[t * 16 + i];
        ceb[t] = c;
    } else if (t < 8) {
        int h = t - 4;
        float c = 0.f;
        for (int i = 0; i < 32; i++) c += We2[h * 32 + i] * ae2[h * 32 + i];
        ceb[t] = c;
    } else if (t < 12) {
        int h = t - 8;
        float c = 0.f;
        for (int i = 0; i < 16; i++) c += We3[h * 16 + i] * ae3[h * 16 + i];
        ceb[t] = c;
    } else if (t == 12) {
        float c = 0.f;
        for (int i = 0; i < 50; i++) c += We4[i] * ae4[i];
        ceb[t] = c;
    }
}

__global__ void k_scan3(int* __restrict__ rowptr, const int* __restrict__ part) {
    int t = threadIdx.x;
    int i = blockIdx.x * 256 + t;
    rowptr[i] = rowptr[i] + part[blockIdx.x];
    if (i == 0) rowptr[NN] = NE;
}

// scatter edges into dst-sorted order (no atomics), packing (src, ew) into one uint
__global__ void k_scatter(const int* __restrict__ src, const float* __restrict__ ew,
                          const int* __restrict__ rowptr, const unsigned int* __restrict__ rkd,
                          unsigned int* __restrict__ ep) {
    int e = blockIdx.x * 256 + threadIdx.x;
    unsigned int u = rkd[e];
    int d = (int)(u & 0x1ffffu);
    int p = rowptr[d] + (int)(u >> 17);
    unsigned int s = (unsigned int)src[e];
    unsigned int q = (unsigned int)(ew[e] * 32767.f + 0.5f);
    __builtin_nontemporal_store((s << 15) | (q & 0x7fffu), &ep[p]);
}

__device__ __forceinline__ void ep_unpack(unsigned int u, int& s, float& w) {
    s = (int)(u >> 15);
    w = (float)(u & 0x7fffu) * (1.f / 32767.f);
}

// ---------------- node transform + fused alpha projections (register-tiled GEMM) ----------------
// TIN = float (layer 1 input) or __half (fp16 inter-layer activations).
template <typename TIN, int FIN, int F, int FR, int H, int C, int ITER>
__global__ __launch_bounds__(256) void k_transform(
    const TIN* __restrict__ in, const float* __restrict__ W,
    const float* __restrict__ as_, const float* __restrict__ ad_,
    __half* __restrict__ h, float* __restrict__ alpha_s, float* __restrict__ alpha_d) {
    constexpr int TF = F / 16;   // features per thread
    constexpr int XS = 65;       // Xl row stride (floats)
    __shared__ float Wl[FIN * F];
    __shared__ float Xl[FIN * XS];
    int t = threadIdx.x;
    int tfg = t & 15;   // feature group
    int ng = t >> 4;    // node group (0..15)
    int f0 = tfg * TF;

    for (int i = t; i < FIN * F; i += 256) {
        int ff = i % F;
        Wl[i] = (ff < FR) ? W[(i / F) * FR + ff] : 0.f;
    }
    float asf[TF], adf[TF];
#pragma unroll
    for (int j = 0; j < TF; j++) {
        bool v = (f0 + j) < FR;
        asf[j] = v ? as_[f0 + j] : 0.f;
        adf[j] = v ? ad_[f0 + j] : 0.f;
    }

    for (int it = 0; it < ITER; ++it) {
        int nb = (blockIdx.x * ITER + it) * 64;
        __syncthreads();
        if constexpr (sizeof(TIN) == 2) {
            for (int p = t; p < 64 * FIN / 2; p += 256) {
                int nn = (2 * p) / FIN, kk = (2 * p) % FIN;
                __half2 v = ((const __half2*)in)[(size_t)(nb + nn) * (FIN / 2) + (kk >> 1)];
                Xl[kk * XS + nn] = __low2float(v);
                Xl[(kk + 1) * XS + nn] = __high2float(v);
            }
        } else {
            for (int i = t; i < 64 * FIN; i += 256) {
                int nn = i / FIN, kk = i % FIN;
                Xl[kk * XS + nn] = (float)in[(size_t)(nb + nn) * FIN + kk];
            }
        }
        __syncthreads();

        float acc[4][TF];
#pragma unroll
        for (int i = 0; i < 4; i++)
#pragma unroll
            for (int j = 0; j < TF; j++) acc[i][j] = 0.f;

#pragma unroll 2
        for (int k = 0; k < FIN; ++k) {
            float4 xv = *(const float4*)&Xl[k * XS + ng * 4];
            float wv[TF];
#pragma unroll
            for (int j4 = 0; j4 < TF; j4 += 4) {
                float4 w4 = *(const float4*)&Wl[k * F + f0 + j4];
                wv[j4] = w4.x; wv[j4 + 1] = w4.y; wv[j4 + 2] = w4.z; wv[j4 + 3] = w4.w;
            }
            const float xs[4] = {xv.x, xv.y, xv.z, xv.w};
#pragma unroll
            for (int i = 0; i < 4; i++)
#pragma unroll
                for (int j = 0; j < TF; j++) acc[i][j] = fmaf(xs[i], wv[j], acc[i][j]);
        }

        // epilogue: h (fp16) + fused alpha projections
#pragma unroll
        for (int i = 0; i < 4; i++) {
            int n = nb + ng * 4 + i;
            __half hv[TF];
            float ps = 0.f, pd = 0.f;
#pragma unroll
            for (int j = 0; j < TF; j++) {
                hv[j] = __float2half(acc[i][j]);
                ps = fmaf(acc[i][j], asf[j], ps);
                pd = fmaf(acc[i][j], adf[j], pd);
            }
            if constexpr (TF == 4) {
                *(uint2*)(h + (size_t)n * F + f0) = *(uint2*)hv;
            } else {
                *(uint4*)(h + (size_t)n * F + f0) = *(uint4*)hv;
            }
            ps += __shfl_xor(ps, 1);
            pd += __shfl_xor(pd, 1);
            ps += __shfl_xor(ps, 2);
            pd += __shfl_xor(pd, 2);
            if constexpr (H == 1) {
                ps += __shfl_xor(ps, 4);
                pd += __shfl_xor(pd, 4);
                ps += __shfl_xor(ps, 8);
                pd += __shfl_xor(pd, 8);
                if (tfg == 0) {
                    alpha_s[n] = ps;
                    alpha_d[n] = pd;
                }
            } else {
                if ((tfg & 3) == 0) {
                    alpha_s[(size_t)n * H + (tfg >> 2)] = ps;
                    alpha_d[(size_t)n * H + (tfg >> 2)] = pd;
                }
            }
        }
    }
}

// ---------------- per-node softmax + aggregation (2 nodes / wave, 8 nodes / block) ----------------
template <int H, int C, bool FINAL>
__global__ __launch_bounds__(256) void k_aggregate(
    const __half* __restrict__ h, const float* __restrict__ asrc, const float* __restrict__ adst,
    const int* __restrict__ rowptr, const unsigned int* __restrict__ ep,
    const float* __restrict__ ceb, const float* __restrict__ b,
    const float* __restrict__ bn_g, const float* __restrict__ bn_b,
    const float* __restrict__ bn_rm, const float* __restrict__ bn_rv,
    __half* __restrict__ out) {
    constexpr int F = H * C;
    constexpr bool P2 = (F > 64);
    constexpr int FSB = P2 ? 256 : 128;  // h row stride in BYTES
    __shared__ float lds_att[4][64 * H];
    __shared__ int lds_off[4][64];

    int wid = threadIdx.x >> 6;
    int lane = threadIdx.x & 63;
    int half = lane >> 5;
    int hl = lane & 31;
    int n = blockIdx.x * 8 + wid * 2 + half;
    int r0 = rowptr[n];
    int r1 = rowptr[n + 1];
    int deg = r1 - r0;

    float ce[H], ad[H];
#pragma unroll
    for (int hh = 0; hh < H; hh++) ce[hh] = ceb[hh];
    if constexpr (H == 4) {
        float4 adv = ((const float4*)adst)[n];
        ad[0] = adv.x; ad[1] = adv.y; ad[2] = adv.z; ad[3] = adv.w;
    } else {
        ad[0] = adst[n];
    }

    // ---- phase 1: one edge per lane (32 lanes per node) ----
    bool val = hl < deg;
    int s_l = 0;
    float w_l = 0.f;
    if (val) ep_unpack(ep[r0 + hl], s_l, w_l);
    float ex_l[H], psum[H];
    if constexpr (H == 4) {
        if (val) {
            float4 v4 = ((const float4*)asrc)[s_l];
            ex_l[0] = __expf(fminf(lrelu(v4.x + ad[0] + w_l * ce[0], 0.2f), 80.f));
            ex_l[1] = __expf(fminf(lrelu(v4.y + ad[1] + w_l * ce[1], 0.2f), 80.f));
            ex_l[2] = __expf(fminf(lrelu(v4.z + ad[2] + w_l * ce[2], 0.2f), 80.f));
            ex_l[3] = __expf(fminf(lrelu(v4.w + ad[3] + w_l * ce[3], 0.2f), 80.f));
        } else {
            ex_l[0] = ex_l[1] = ex_l[2] = ex_l[3] = 0.f;
        }
    } else {
        ex_l[0] = val ? __expf(fminf(lrelu(asrc[s_l] + ad[0] + w_l * ce[0], 0.2f), 80.f)) : 0.f;
    }
#pragma unroll
    for (int hh = 0; hh < H; hh++) psum[hh] = ex_l[hh];
    // overflow edges (deg > 32, rare): add into denom (per half-wave)
    for (int r = r0 + 32 + hl; r < r1; r += 32) {
        int s;
        float w;
        ep_unpack(ep[r], s, w);
        if constexpr (H == 4) {
            float4 v4 = ((const float4*)asrc)[s];
            psum[0] += __expf(fminf(lrelu(v4.x + ad[0] + w * ce[0], 0.2f), 80.f));
            psum[1] += __expf(fminf(lrelu(v4.y + ad[1] + w * ce[1], 0.2f), 80.f));
            psum[2] += __expf(fminf(lrelu(v4.z + ad[2] + w * ce[2], 0.2f), 80.f));
            psum[3] += __expf(fminf(lrelu(v4.w + ad[3] + w * ce[3], 0.2f), 80.f));
        } else {
            psum[0] += __expf(fminf(lrelu(asrc[s] + ad[0] + w * ce[0], 0.2f), 80.f));
        }
    }
    float rden[H];
#pragma unroll
    for (int hh = 0; hh < H; hh++) {
        float v = psum[hh];
#pragma unroll
        for (int off = 16; off >= 1; off >>= 1) v += __shfl_xor(v, off);  // half-wave reduce
        rden[hh] = 1.f / (v + 1e-16f);
    }

    // stage att = ex/den and row byte-offset in LDS (32 slots per node, all initialized)
    lds_off[wid][lane] = s_l * FSB;
#pragma unroll
    for (int hh = 0; hh < H; hh++) lds_att[wid][lane * H + hh] = ex_l[hh] * rden[hh];
    __syncthreads();

    int jn = deg < 32 ? deg : 32;
    int base = half * 32;
    const char* hb = (const char*)h;

    if constexpr (P2) {
        // F=128: 16 lanes/edge, 8 features (uint4) per lane, 2 edges/iter per node
        int flane = hl & 15;
        int grp = hl >> 4;
        int f0 = 8 * flane;
        int hsel = f0 >> 5;  // C=32
        float a[8];
#pragma unroll
        for (int i = 0; i < 8; i++) a[i] = 0.f;
#pragma unroll 4
        for (int j = 0; j < jn; j += 2) {
            int je = base + j + grp;
            int off = lds_off[wid][je];
            float att = lds_att[wid][je * H + hsel];
            uint4 p = *(const uint4*)(hb + (size_t)(off + flane * 16));
            const __half2* hp = (const __half2*)&p;
#pragma unroll
            for (int i = 0; i < 4; i++) {
                a[2 * i] = fmaf(__low2float(hp[i]), att, a[2 * i]);
                a[2 * i + 1] = fmaf(__high2float(hp[i]), att, a[2 * i + 1]);
            }
        }
        if (deg > 32) {  // rare
            float rdensel = sel_h<H>(rden, hsel);
            for (int r = r0 + 32; r < r1; ++r) {
                unsigned int u = ep[r];
                int s;
                float w;
                ep_unpack(u, s, w);
                float4 v4 = ((const float4*)asrc)[s];
                float aA[4];
                aA[0] = fminf(lrelu(v4.x + ad[0] + w * ce[0], 0.2f), 80.f);
                aA[1] = fminf(lrelu(v4.y + ad[1] + w * ce[1], 0.2f), 80.f);
                aA[2] = fminf(lrelu(v4.z + ad[2] + w * ce[2], 0.2f), 80.f);
                aA[3] = fminf(lrelu(v4.w + ad[3] + w * ce[3], 0.2f), 80.f);
                float att = __expf(sel_h<H>(aA, hsel)) * rdensel;
                att = (grp == 0) ? att : 0.f;
                uint4 p = *(const uint4*)(hb + (size_t)(s * FSB + flane * 16));
                const __half2* hp = (const __half2*)&p;
#pragma unroll
                for (int i = 0; i < 4; i++) {
                    a[2 * i] = fmaf(__low2float(hp[i]), att, a[2 * i]);
                    a[2 * i + 1] = fmaf(__high2float(hp[i]), att, a[2 * i + 1]);
                }
            }
        }
#pragma unroll
        for (int i = 0; i < 8; i++) a[i] += __shfl_xor(a[i], 16);
        if (hl < 16) {
            __half ho[8];
#pragma unroll
            for (int i = 0; i < 8; i++) ho[i] = __float2half(lrelu(a[i] + b[f0 + i], 0.01f));
            ((uint4*)out)[(size_t)n * 16 + flane] = *(uint4*)ho;
        }
    } else {
        // F<=64: 8 lanes/edge, 8 features (uint4) per lane, 4 edges/iter per node
        int flane = hl & 7;
        int grp = hl >> 3;
        int f0 = 8 * flane;
        int hsel = (H == 1) ? 0 : (f0 >> 4);  // C=16
        float a[8];
#pragma unroll
        for (int i = 0; i < 8; i++) a[i] = 0.f;
#pragma unroll 4
        for (int j = 0; j < jn; j += 4) {
            int je = base + j + grp;
            int off = lds_off[wid][je];
            float att = lds_att[wid][je * H + hsel];
            uint4 p = *(const uint4*)(hb + (size_t)(off + flane * 16));
            const __half2* hp = (const __half2*)&p;
#pragma unroll
            for (int i = 0; i < 4; i++) {
                a[2 * i] = fmaf(__low2float(hp[i]), att, a[2 * i]);
                a[2 * i + 1] = fmaf(__high2float(hp[i]), att, a[2 * i + 1]);
            }
        }
        if (deg > 32) {  // rare
            float rdensel = sel_h<H>(rden, hsel);
            for (int r = r0 + 32; r < r1; ++r) {
                unsigned int u = ep[r];
                int s;
                float w;
                ep_unpack(u, s, w);
                float aA[H];
                if constexpr (H == 4) {
                    float4 v4 = ((const float4*)asrc)[s];
                    aA[0] = fminf(lrelu(v4.x + ad[0] + w * ce[0], 0.2f), 80.f);
                    aA[1] = fminf(lrelu(v4.y + ad[1] + w * ce[1], 0.2f), 80.f);
                    aA[2] = fminf(lrelu(v4.z + ad[2] + w * ce[2], 0.2f), 80.f);
                    aA[3] = fminf(lrelu(v4.w + ad[3] + w * ce[3], 0.2f), 80.f);
                } else {
                    aA[0] = fminf(lrelu(asrc[s] + ad[0] + w * ce[0], 0.2f), 80.f);
                }
                float att = __expf(sel_h<H>(aA, hsel)) * rdensel;
                att = (grp == 0) ? att : 0.f;
                uint4 p = *(const uint4*)(hb + (size_t)(s * FSB + flane * 16));
                const __half2* hp = (const __half2*)&p;
#pragma unroll
                for (int i = 0; i < 4; i++) {
                    a[2 * i] = fmaf(__low2float(hp[i]), att, a[2 * i]);
                    a[2 * i + 1] = fmaf(__high2float(hp[i]), att, a[2 * i + 1]);
                }
            }
        }
#pragma unroll
        for (int i = 0; i < 8; i++) {
            a[i] += __shfl_xor(a[i], 8);
            a[i] += __shfl_xor(a[i], 16);
        }
        if constexpr (FINAL) {
            if (hl < 7) {
                __half ho[8];
#pragma unroll
                for (int k = 0; k < 8; k++) {
                    int f = f0 + k;
                    float o = 0.f;
                    if (f < 50) {
                        float v = a[k] + b[f];
                        v = (v - bn_rm[f]) * rsqrtf(bn_rv[f] + 1e-5f) * bn_g[f] + bn_b[f];
                        o = lrelu(v, 0.01f);
                    }
                    ho[k] = __float2half(o);
                }
                ((uint4*)out)[(size_t)n * 8 + hl] = *(uint4*)ho;
            }
        } else {
            if (hl < 8) {
                __half ho[8];
#pragma unroll
                for (int i = 0; i < 8; i++) ho[i] = __float2half(lrelu(a[i] + b[f0 + i], 0.01f));
                ((uint4*)out)[(size_t)n * 8 + flane] = *(uint4*)ho;
            }
        }
    }
}

// ---------------- graph pooling: one wave/graph, sorted batch (binary search), fp16 reads ----------------
__global__ __launch_bounds__(256) void k_pool(const __half* __restrict__ nodeout, const int* __restrict__ batch,
                                              float* __restrict__ gbuf) {
    int wid = threadIdx.x >> 6;
    int lane = threadIdx.x & 63;
    int g = blockIdx.x * 4 + wid;
    int lo = 0, hi = NN;
    while (lo < hi) {
        int mid = (lo + hi) >> 1;
        if (batch[mid] < g) lo = mid + 1; else hi = mid;
    }
    int s0 = lo;
    hi = NN;
    while (lo < hi) {
        int mid = (lo + hi) >> 1;
        if (batch[mid] < g + 1) lo = mid + 1; else hi = mid;
    }
    int s1 = lo;
    if (lane < 50) {
        float acc = 0.f;
        for (int n = s0; n < s1; ++n) acc += __half2float(nodeout[(size_t)n * 64 + lane]);
        gbuf[(size_t)g * 50 + lane] = acc;
    }
}

// ---------------- final MLP over graphs: 64 threads/block, 1 graph/thread, LDS-staged ----------------
__global__ __launch_bounds__(64) void k_mlp(const float* __restrict__ gbuf,
                      const float* __restrict__ Wf1, const float* __restrict__ bf1,
                      const float* __restrict__ Wf2, const float* __restrict__ bf2,
                      const float* __restrict__ Wf3, const float* __restrict__ bf3,
                      float* __restrict__ out) {
    __shared__ float W1[1500], W2[600], W3[40], B1[30], B2[20], B3[2];
    __shared__ float G[64 * 50];
    int t = threadIdx.x;
    for (int i = t; i < 1500; i += 64) W1[i] = Wf1[i];
    for (int i = t; i < 600; i += 64) W2[i] = Wf2[i];
    if (t < 40) W3[t] = Wf3[t];
    if (t < 30) B1[t] = bf1[t];
    if (t < 20) B2[t] = bf2[t];
    if (t < 2) B3[t] = bf3[t];
    int g0 = blockIdx.x * 64;
    for (int i = t; i < 64 * 50; i += 64) G[i] = gbuf[(size_t)g0 * 50 + i];
    __syncthreads();
    float gv[50];
#pragma unroll
    for (int i = 0; i < 50; i++) gv[i] = G[t * 50 + i];
    float h1[30];
#pragma unroll
    for (int j = 0; j < 30; j++) {
        float a = B1[j];
#pragma unroll
        for (int i = 0; i < 50; i++) a += gv[i] * W1[i * 30 + j];
        h1[j] = lrelu(a, 0.01f);
    }
    float h2[20];
#pragma unroll
    for (int j = 0; j < 20; j++) {
        float a = B2[j];
#pragma unroll
        for (int i = 0; i < 30; i++) a += h1[i] * W2[i * 20 + j];
        h2[j] = lrelu(a, 0.01f);
    }
    int g = g0 + t;
    float o0 = B3[0], o1 = B3[1];
#pragma unroll
    for (int i = 0; i < 20; i++) {
        o0 += h2[i] * W3[i * 2];
        o1 += h2[i] * W3[i * 2 + 1];
    }
    ((float2*)out)[g] = make_float2(o0, o1);
}

extern "C" void kernel_launch(void* const* d_in, const int* in_sizes, int n_in,
                              void* d_out, int out_size, void* d_ws, size_t ws_size,
                              hipStream_t stream) {
    const float* x = (const float*)d_in[0];
    const int* ei = (const int*)d_in[1];
    const float* ew = (const float*)d_in[2];
    const int* batch = (const int*)d_in[3];
    const float* W1 = (const float*)d_in[4];
    const float* as1 = (const float*)d_in[5];
    const float* ad1 = (const float*)d_in[6];
    const float* We1 = (const float*)d_in[7];
    const float* ae1 = (const float*)d_in[8];
    const float* b1 = (const float*)d_in[9];
    const float* W2 = (const float*)d_in[10];
    const float* as2 = (const float*)d_in[11];
    const float* ad2 = (const float*)d_in[12];
    const float* We2 = (const float*)d_in[13];
    const float* ae2 = (const float*)d_in[14];
    const float* b2 = (const float*)d_in[15];
    const float* W3 = (const float*)d_in[16];
    const float* as3 = (const float*)d_in[17];
    const float* ad3 = (const float*)d_in[18];
    const float* We3 = (const float*)d_in[19];
    const float* ae3 = (const float*)d_in[20];
    const float* b3 = (const float*)d_in[21];
    const float* W4 = (const float*)d_in[22];
    const float* as4 = (const float*)d_in[23];
    const float* ad4 = (const float*)d_in[24];
    const float* We4 = (const float*)d_in[25];
    const float* ae4 = (const float*)d_in[26];
    const float* b4 = (const float*)d_in[27];
    const float* bn_g = (const float*)d_in[28];
    const float* bn_b = (const float*)d_in[29];
    const float* bn_rm = (const float*)d_in[30];
    const float* bn_rv = (const float*)d_in[31];
    const float* Wf1 = (const float*)d_in[32];
    const float* bf1 = (const float*)d_in[33];
    const float* Wf2 = (const float*)d_in[34];
    const float* bf2 = (const float*)d_in[35];
    const float* Wf3 = (const float*)d_in[36];
    const float* bf3 = (const float*)d_in[37];
    float* out = (float*)d_out;

    const int* src = ei;
    const int* dst = ei + NE;

    // workspace layout
    char* ws = (char*)d_ws;
    __half* feat = (__half*)ws;       ws += (size_t)NN * 128 * 2;  // 32 MB fp16 activations
    __half* hbuf = (__half*)ws;       ws += (size_t)NN * 128 * 2;  // 32 MB fp16 transformed h
    float* as_buf = (float*)ws;       ws += (size_t)NN * 4 * 4;
    float* ad_buf = (float*)ws;       ws += (size_t)NN * 4 * 4;
    int* cnt = (int*)ws;              ws += (size_t)NN * 4;
    int* rowptr = (int*)ws;           ws += (size_t)(NN + 64) * 4;
    unsigned int* ep = (unsigned int*)ws; ws += (size_t)NE * 4;
    int* part = (int*)ws;             ws += 512 * 4;
    float* ce_buf = (float*)ws;       ws += 64 * 4;
    float* gbuf = (float*)ws;         ws += (size_t)NG * 50 * 4;
    // rkd reuses hbuf (free until layer-1 transform, which runs after scatter)
    unsigned int* rkd = (unsigned int*)hbuf;

    // CSR build + per-layer edge constants
    hipMemsetAsync(cnt, 0, (size_t)NN * 4, stream);
    k_hist<<<NE / 256, 256, 0, stream>>>(dst, cnt, rkd);
    k_scan1<<<NN / 256, 256, 0, stream>>>(cnt, rowptr, part);
    k_scan2<<<1, 512, 0, stream>>>(part, We1, ae1, We2, ae2, We3, ae3, We4, ae4, ce_buf);
    k_scan3<<<NN / 256, 256, 0, stream>>>(rowptr, part);
    k_scatter<<<NE / 256, 256, 0, stream>>>(src, ew, rowptr, rkd, ep);

    // layer 1: fin=6, H=4, C=16 (F=64)
    k_transform<float, 6, 64, 64, 4, 16, 4><<<NN / 256, 256, 0, stream>>>(x, W1, as1, ad1, hbuf, as_buf, ad_buf);
    k_aggregate<4, 16, false><<<NN / 8, 256, 0, stream>>>(hbuf, as_buf, ad_buf, rowptr, ep, ce_buf,
                                                          b1, nullptr, nullptr, nullptr, nullptr, feat);
    // layer 2: fin=64, H=4, C=32 (F=128)
    k_transform<__half, 64, 128, 128, 4, 32, 4><<<NN / 256, 256, 0, stream>>>(feat, W2, as2, ad2, hbuf, as_buf, ad_buf);
    k_aggregate<4, 32, false><<<NN / 8, 256, 0, stream>>>(hbuf, as_buf, ad_buf, rowptr, ep, ce_buf + 4,
                                                          b2, nullptr, nullptr, nullptr, nullptr, feat);
    // layer 3: fin=128, H=4, C=16 (F=64)
    k_transform<__half, 128, 64, 64, 4, 16, 4><<<NN / 256, 256, 0, stream>>>(feat, W3, as3, ad3, hbuf, as_buf, ad_buf);
    k_aggregate<4, 16, false><<<NN / 8, 256, 0, stream>>>(hbuf, as_buf, ad_buf, rowptr, ep, ce_buf + 8,
                                                          b3, nullptr, nullptr, nullptr, nullptr, feat);
    // layer 4: fin=64, F padded 50->64, H=1, fused bias+BN+lrelu, fp16 per-node out
    k_transform<__half, 64, 64, 50, 1, 50, 4><<<NN / 256, 256, 0, stream>>>(feat, W4, as4, ad4, hbuf, as_buf, ad_buf);
    k_aggregate<1, 50, true><<<NN / 8, 256, 0, stream>>>(hbuf, as_buf, ad_buf, rowptr, ep, ce_buf + 12,
                                                         b4, bn_g, bn_b, bn_rm, bn_rv, feat);
    // graph pooling + final MLP
    k_pool<<<NG / 4, 256, 0, stream>>>(feat, batch, gbuf);
    k_mlp<<<NG / 64, 64, 0, stream>>>(gbuf, Wf1, bf1, Wf2, bf2, Wf3, bf3, out);
}